// Round 8
// baseline (161.690 us; speedup 1.0000x reference)
//
#include <hip/hip_runtime.h>
#include <math.h>

#define NROWS 8192
#define FIN   512
#define FOUT  256
#define NCHUNK 256
#define CHROWS 32   // NROWS / NCHUNK

typedef _Float16 f16;
typedef _Float16 f16x8 __attribute__((ext_vector_type(8)));
typedef float    f32x4 __attribute__((ext_vector_type(4)));

// ---- prep: x -> f16, W -> Wt f16 transposed [N][K]; blocks 256-319 zero fg ----
__global__ __launch_bounds__(256) void prep(const float* __restrict__ x,
                                            const float* __restrict__ W,
                                            f16* __restrict__ xh,
                                            f16* __restrict__ Wt,
                                            float* __restrict__ fg) {
    const int b = blockIdx.x, t = threadIdx.x;
    if (b < 256) {
        const size_t base = (size_t)b * 16384;
#pragma unroll 4
        for (int i = 0; i < 16; ++i) {
            const size_t idx = base + (size_t)i * 1024 + t * 4;
            float4 v = *(const float4*)&x[idx];
            union { f16 h[4]; ushort4 u; } cv;
            cv.h[0] = (f16)v.x; cv.h[1] = (f16)v.y;
            cv.h[2] = (f16)v.z; cv.h[3] = (f16)v.w;
            *(ushort4*)&xh[idx] = cv.u;
        }
    } else {
        const int n = b - 256;   // 0..255
        Wt[(size_t)n * FIN + t]       = (f16)W[(size_t)t * FOUT + n];
        Wt[(size_t)n * FIN + t + 256] = (f16)W[(size_t)(t + 256) * FOUT + n];
        if (n < 64) fg[n * 256 + t] = 0.f;   // zero f and g
    }
}

// ---- GEMM h = x@W via f16 MFMA, BK=128 (R6-proven); fused f/g epilogue ----
__global__ __launch_bounds__(256) void gemm_fg(const f16* __restrict__ xh,
                                               const f16* __restrict__ Wt,
                                               const float* __restrict__ a,
                                               float* __restrict__ h,
                                               float* __restrict__ f,
                                               float* __restrict__ g) {
    __shared__ __align__(16) f16 As[64][136];
    __shared__ __align__(16) f16 Bs[64][136];
    __shared__ float sf[2][64], sg[2][64];
    const int tid = threadIdx.x;
    const int n0 = blockIdx.x * 64;
    const int m0 = blockIdx.y * 64;
    const int srow = tid >> 2, sseg = (tid & 3) * 8;
    const int w = tid >> 6, lane = tid & 63;
    const int wm = (w & 1) * 32, wn = (w >> 1) * 32;
    const int l15 = lane & 15, quad = lane >> 4;

    f16x8 pa[4], pb[4];
#pragma unroll
    for (int j = 0; j < 4; ++j) {
        pa[j] = *(const f16x8*)&xh[(size_t)(m0 + srow) * FIN + j * 32 + sseg];
        pb[j] = *(const f16x8*)&Wt[(size_t)(n0 + srow) * FIN + j * 32 + sseg];
    }

    f32x4 acc[2][2] = {};
    for (int k0 = 0; k0 < FIN; k0 += 128) {
        __syncthreads();
#pragma unroll
        for (int j = 0; j < 4; ++j) {
            *(f16x8*)&As[srow][j * 32 + sseg] = pa[j];
            *(f16x8*)&Bs[srow][j * 32 + sseg] = pb[j];
        }
        __syncthreads();
        if (k0 + 128 < FIN) {
#pragma unroll
            for (int j = 0; j < 4; ++j) {
                pa[j] = *(const f16x8*)&xh[(size_t)(m0 + srow) * FIN + k0 + 128 + j * 32 + sseg];
                pb[j] = *(const f16x8*)&Wt[(size_t)(n0 + srow) * FIN + k0 + 128 + j * 32 + sseg];
            }
        }
#pragma unroll
        for (int kk = 0; kk < 4; ++kk) {
            f16x8 af[2], bf[2];
#pragma unroll
            for (int ti = 0; ti < 2; ++ti)
                af[ti] = *(const f16x8*)&As[wm + ti * 16 + l15][kk * 32 + quad * 8];
#pragma unroll
            for (int tj = 0; tj < 2; ++tj)
                bf[tj] = *(const f16x8*)&Bs[wn + tj * 16 + l15][kk * 32 + quad * 8];
#pragma unroll
            for (int ti = 0; ti < 2; ++ti)
#pragma unroll
                for (int tj = 0; tj < 2; ++tj)
                    acc[ti][tj] = __builtin_amdgcn_mfma_f32_16x16x32_f16(af[ti], bf[tj], acc[ti][tj], 0, 0, 0);
        }
    }
#pragma unroll
    for (int ti = 0; ti < 2; ++ti)
#pragma unroll
        for (int tj = 0; tj < 2; ++tj) {
            const int col = n0 + wn + tj * 16 + l15;
#pragma unroll
            for (int r = 0; r < 4; ++r) {
                const int row = m0 + wm + ti * 16 + quad * 4 + r;
                h[(size_t)row * FOUT + col] = acc[ti][tj][r];
            }
        }
    const float a1c0 = a[n0 + wn + l15];
    const float a1c1 = a[n0 + wn + 16 + l15];
    const float a2c0 = a[FOUT + n0 + wn + l15];
    const float a2c1 = a[FOUT + n0 + wn + 16 + l15];
    const int wnIdx = w >> 1;
#pragma unroll
    for (int ti = 0; ti < 2; ++ti) {
        float pf[4], pg[4];
#pragma unroll
        for (int r = 0; r < 4; ++r) {
            pf[r] = acc[ti][0][r] * a1c0 + acc[ti][1][r] * a1c1;
            pg[r] = acc[ti][0][r] * a2c0 + acc[ti][1][r] * a2c1;
        }
#pragma unroll
        for (int off = 8; off >= 1; off >>= 1)
#pragma unroll
            for (int r = 0; r < 4; ++r) {
                pf[r] += __shfl_xor(pf[r], off, 16);
                pg[r] += __shfl_xor(pg[r], off, 16);
            }
        if (l15 == 0)
#pragma unroll
            for (int r = 0; r < 4; ++r) {
                sf[wnIdx][wm + ti * 16 + quad * 4 + r] = pf[r];
                sg[wnIdx][wm + ti * 16 + quad * 4 + r] = pg[r];
            }
    }
    __syncthreads();
    if (tid < 64) {
        atomicAdd(&f[m0 + tid], sf[0][tid] + sf[1][tid]);
        atomicAdd(&g[m0 + tid], sg[0][tid] + sg[1][tid]);
    }
}

// ---- rank both g (ascending) and f (descending); exact bijection via index tie ----
__global__ __launch_bounds__(256) void rank_gf(const float* __restrict__ g,
                                               const float* __restrict__ f,
                                               float* __restrict__ gs,
                                               int* __restrict__ perm,
                                               float* __restrict__ fss,
                                               int* __restrict__ fperm) {
    const int t = threadIdx.x, b = blockIdx.x;
    const int jl = t & 31, seg = t >> 5;
    __shared__ int part[8][32];
    if (b < 256) {
        const int j = b * 32 + jl;
        const float gj = g[j];
        const int base = seg * (NROWS / 8);
        int cnt = 0;
        for (int r = 0; r < NROWS / 8; r += 4) {
            const float4 v = *(const float4*)&g[base + r];
            const int i0 = base + r;
            cnt += (v.x < gj) || (v.x == gj && (i0 + 0) < j);
            cnt += (v.y < gj) || (v.y == gj && (i0 + 1) < j);
            cnt += (v.z < gj) || (v.z == gj && (i0 + 2) < j);
            cnt += (v.w < gj) || (v.w == gj && (i0 + 3) < j);
        }
        part[seg][jl] = cnt;
        __syncthreads();
        if (seg == 0) {
            int rank = 0;
#pragma unroll
            for (int s = 0; s < 8; ++s) rank += part[s][jl];
            gs[rank] = gj;
            perm[rank] = j;
        }
    } else {
        const int j = (b - 256) * 32 + jl;
        const float fj = f[j];
        const int base = seg * (NROWS / 8);
        int cnt = 0;
        for (int r = 0; r < NROWS / 8; r += 4) {
            const float4 v = *(const float4*)&f[base + r];
            const int i0 = base + r;
            cnt += (v.x > fj) || (v.x == fj && (i0 + 0) < j);
            cnt += (v.y > fj) || (v.y == fj && (i0 + 1) < j);
            cnt += (v.z > fj) || (v.z == fj && (i0 + 2) < j);
            cnt += (v.w > fj) || (v.w == fj && (i0 + 3) < j);
        }
        part[seg][jl] = cnt;
        __syncthreads();
        if (seg == 0) {
            int rank = 0;
#pragma unroll
            for (int s = 0; s < 8; ++s) rank += part[s][jl];
            fss[rank] = fj;     // f sorted descending
            fperm[rank] = j;
        }
    }
}

// ---- scan pass 1 (blocks 0-255): per-chunk sums; blocks 256-287: n0sorted ----
__global__ __launch_bounds__(256) void scan_pass1(const float* __restrict__ h,
                                                  const int* __restrict__ perm,
                                                  const float* __restrict__ gs,
                                                  const float* __restrict__ fss,
                                                  float* __restrict__ c0,
                                                  float* __restrict__ c1,
                                                  float* __restrict__ c1s,
                                                  int* __restrict__ n0sorted) {
    const int b = blockIdx.x, c = threadIdx.x;
    if (b < 256) {
        const int base = b * CHROWS;
        __shared__ int p[CHROWS];
        __shared__ float wl[CHROWS];
        if (c < CHROWS) {
            p[c] = perm[base + c];
            wl[c] = expf(gs[base + c] - gs[NROWS - 1]);
        }
        __syncthreads();
        float s0 = 0.f, s1 = 0.f;
        for (int r = 0; r < CHROWS; ++r) {
            float v = h[(size_t)p[r] * FOUT + c];
            s0 += v;
            s1 += wl[r] * v;
        }
        c0[b * FOUT + c] = s0;
        c1[b * FOUT + c] = s1;
        if (c == 0) {
            float t = 0.f;
            for (int r = 0; r < CHROWS; ++r) t += wl[r];
            c1s[b] = t;
        }
    } else {
        const int r = (b - 256) * 256 + c;    // 0..8191, descending-f order
        const float tt = -fss[r];
        int lo = 0, hi = NROWS;
        while (lo < hi) {
            int mid = (lo + hi) >> 1;
            if (gs[mid] <= tt) lo = mid + 1; else hi = mid;
        }
        n0sorted[r] = lo;                     // monotone non-decreasing in r
    }
}

// ---- scan pass 2: chunk-level PREFIX scans for c0, c1, c1s (+ totals) ----
__global__ __launch_bounds__(256) void scan_pass2(const float* __restrict__ c0,
                                                  const float* __restrict__ c1,
                                                  const float* __restrict__ c1s,
                                                  float* __restrict__ o0,
                                                  float* __restrict__ o1q,
                                                  float* __restrict__ oq1s,
                                                  float* __restrict__ T1,
                                                  float* __restrict__ T1s) {
    const int b = blockIdx.x, t = threadIdx.x;
    __shared__ float sb[NCHUNK];
    if (b < 256) {
        const float cv = c0[t * FOUT + b];
        sb[t] = cv;
        __syncthreads();
        for (int off = 1; off < NCHUNK; off <<= 1) {
            float add = (t >= off) ? sb[t - off] : 0.f;
            __syncthreads();
            sb[t] += add;
            __syncthreads();
        }
        o0[t * FOUT + b] = sb[t] - cv;
    } else if (b < 512) {
        const int c = b - 256;
        const float cv = c1[t * FOUT + c];
        sb[t] = cv;
        __syncthreads();
        for (int off = 1; off < NCHUNK; off <<= 1) {
            float add = (t >= off) ? sb[t - off] : 0.f;
            __syncthreads();
            sb[t] += add;
            __syncthreads();
        }
        o1q[t * FOUT + c] = sb[t] - cv;       // exclusive prefix of c1
        if (t == NCHUNK - 1) T1[c] = sb[t];   // column total
    } else {
        const float cv = c1s[t];
        sb[t] = cv;
        __syncthreads();
        for (int off = 1; off < NCHUNK; off <<= 1) {
            float add = (t >= off) ? sb[t - off] : 0.f;
            __syncthreads();
            sb[t] += add;
            __syncthreads();
        }
        oq1s[t] = sb[t] - cv;
        if (t == NCHUNK - 1) T1s[0] = sb[t];
    }
}

// ---- scan3+final fused: sweep ranks, emit outputs at their n0 positions.
//      P0 = running prefix; S1[n0] = T1 - Q1[n0] (suffix = total - prefix). ----
__global__ __launch_bounds__(256) void scan3_final(const float* __restrict__ h,
                                                   const int* __restrict__ perm,
                                                   const float* __restrict__ gs,
                                                   const float* __restrict__ fss,
                                                   const int* __restrict__ fperm,
                                                   const int* __restrict__ n0sorted,
                                                   const float* __restrict__ o0,
                                                   const float* __restrict__ o1q,
                                                   const float* __restrict__ oq1s,
                                                   const float* __restrict__ T1,
                                                   const float* __restrict__ T1s,
                                                   float* __restrict__ out) {
    const int k = blockIdx.x, c = threadIdx.x;
    const int base = k * CHROWS;
    __shared__ int p[CHROWS];
    __shared__ float wl[CHROWS];
    if (c < CHROWS) {
        p[c] = perm[base + c];
        wl[c] = expf(gs[base + c] - gs[NROWS - 1]);
    }
    __syncthreads();
    // emission window: output-list indices with n0sorted in [base, base+32)
    int lo;
    {
        int l = 0, hh = NROWS;
        while (l < hh) { int mid = (l + hh) >> 1; if (n0sorted[mid] < base) l = mid + 1; else hh = mid; }
        lo = l;
    }
    int hi;
    if (k == NCHUNK - 1) hi = NROWS;
    else {
        int l = lo, hh = NROWS;
        const int lim = base + CHROWS;
        while (l < hh) { int mid = (l + hh) >> 1; if (n0sorted[mid] < lim) l = mid + 1; else hh = mid; }
        hi = l;
    }
    float v[CHROWS];
#pragma unroll
    for (int r = 0; r < CHROWS; ++r) v[r] = h[(size_t)p[r] * FOUT + c];

    float run0  = o0[k * FOUT + c];    // P0 at rank=base (exclusive prefix)
    float runq  = o1q[k * FOUT + c];   // Q1 at rank=base
    float runqs = oq1s[k];             // Q1s at rank=base (scalar)
    const float T1c = T1[c], T1ss = T1s[0], gm = gs[NROWS - 1];

    int idx = lo;
    for (int r = 0; r < CHROWS; ++r) {
        const int rank = base + r;
        while (idx < hi && n0sorted[idx] == rank) {     // block-uniform loop
            const float fi = fss[idx];
            const int   i  = fperm[idx];
            const float m  = fmaxf(0.f, fi + gm);
            const float A  = expf(-m);
            const float B  = expf(fi + gm - m);
            const float denom = A * (float)rank + B * (T1ss - runqs);
            const float vo = (A * run0 + B * (T1c - runq)) / denom;
            out[(size_t)i * FOUT + c] = vo > 0.f ? vo : expm1f(vo);
            ++idx;
        }
        run0  += v[r];
        runq  += wl[r] * v[r];
        runqs += wl[r];
    }
    if (k == NCHUNK - 1) {
        // remaining outputs have n0 == NROWS; running sums now equal totals
        while (idx < NROWS) {
            const float fi = fss[idx];
            const int   i  = fperm[idx];
            const float m  = fmaxf(0.f, fi + gm);
            const float A  = expf(-m);
            const float B  = expf(fi + gm - m);
            const float denom = A * (float)NROWS + B * (T1ss - runqs);
            const float vo = (A * run0 + B * (T1c - runq)) / denom;
            out[(size_t)i * FOUT + c] = vo > 0.f ? vo : expm1f(vo);
            ++idx;
        }
    }
}

extern "C" void kernel_launch(void* const* d_in, const int* in_sizes, int n_in,
                              void* d_out, int out_size, void* d_ws, size_t ws_size,
                              hipStream_t stream) {
    (void)in_sizes; (void)n_in; (void)out_size; (void)ws_size;
    const float* x = (const float*)d_in[0];
    const float* W = (const float*)d_in[1];
    const float* a = (const float*)d_in[2];
    float* out = (float*)d_out;

    char* ws = (char*)d_ws;
    size_t off = 0;
    auto alloc = [&](size_t bytes) -> void* {
        void* p = ws + off;
        off += (bytes + 255) & ~(size_t)255;
        return p;
    };
    f16*   xh    = (f16*)alloc((size_t)NROWS * FIN * 2);
    f16*   Wt    = (f16*)alloc((size_t)FOUT * FIN * 2);
    float* h     = (float*)alloc((size_t)NROWS * FOUT * 4);
    float* fg    = (float*)alloc(2 * NROWS * 4);
    float* f     = fg;
    float* g     = fg + NROWS;
    float* gs    = (float*)alloc(NROWS * 4);
    int*   perm  = (int*)alloc(NROWS * 4);
    float* fss   = (float*)alloc(NROWS * 4);
    int*   fperm = (int*)alloc(NROWS * 4);
    int*   n0sorted = (int*)alloc(NROWS * 4);
    float* c0    = (float*)alloc(NCHUNK * FOUT * 4);
    float* c1    = (float*)alloc(NCHUNK * FOUT * 4);
    float* c1s   = (float*)alloc(NCHUNK * 4);
    float* o0    = (float*)alloc(NCHUNK * FOUT * 4);
    float* o1q   = (float*)alloc(NCHUNK * FOUT * 4);
    float* oq1s  = (float*)alloc(NCHUNK * 4);
    float* T1    = (float*)alloc(FOUT * 4);
    float* T1s   = (float*)alloc(4);

    prep<<<512, 256, 0, stream>>>(x, W, xh, Wt, fg);
    gemm_fg<<<dim3(FOUT / 64, NROWS / 64), 256, 0, stream>>>(xh, Wt, a, h, f, g);
    rank_gf<<<512, 256, 0, stream>>>(g, f, gs, perm, fss, fperm);
    scan_pass1<<<288, 256, 0, stream>>>(h, perm, gs, fss, c0, c1, c1s, n0sorted);
    scan_pass2<<<513, 256, 0, stream>>>(c0, c1, c1s, o0, o1q, oq1s, T1, T1s);
    scan3_final<<<NCHUNK, 256, 0, stream>>>(h, perm, gs, fss, fperm, n0sorted,
                                            o0, o1q, oq1s, T1, T1s, out);
}

// Round 9
// 135.234 us; speedup vs baseline: 1.1956x; 1.1956x over previous
//
#include <hip/hip_runtime.h>
#include <math.h>

#define NROWS 8192
#define FIN   512
#define FOUT  256
#define NCHUNK 512
#define CHROWS 16   // NROWS / NCHUNK

typedef _Float16 f16;
typedef _Float16 f16x8 __attribute__((ext_vector_type(8)));
typedef float    f32x4 __attribute__((ext_vector_type(4)));

// ---- prep: x -> f16, W -> Wt f16 transposed [N][K]; zero fg ----
__global__ __launch_bounds__(256) void prep(const float* __restrict__ x,
                                            const float* __restrict__ W,
                                            f16* __restrict__ xh,
                                            f16* __restrict__ Wt,
                                            float* __restrict__ fg) {
    const int b = blockIdx.x, t = threadIdx.x;
    if (b < 256) {
        const size_t base = (size_t)b * 16384;
#pragma unroll 4
        for (int i = 0; i < 16; ++i) {
            const size_t idx = base + (size_t)i * 1024 + t * 4;
            float4 v = *(const float4*)&x[idx];
            union { f16 h[4]; ushort4 u; } cv;
            cv.h[0] = (f16)v.x; cv.h[1] = (f16)v.y;
            cv.h[2] = (f16)v.z; cv.h[3] = (f16)v.w;
            *(ushort4*)&xh[idx] = cv.u;
        }
    } else {
        const int n = b - 256;   // 0..255
        Wt[(size_t)n * FIN + t]       = (f16)W[(size_t)t * FOUT + n];
        Wt[(size_t)n * FIN + t + 256] = (f16)W[(size_t)(t + 256) * FOUT + n];
        if (n < 64) fg[n * 256 + t] = 0.f;   // zero f and g
    }
}

// ---- GEMM h = x@W via f16 MFMA, BK=128 (R6-proven); h stored f16 ----
__global__ __launch_bounds__(256) void gemm_fg(const f16* __restrict__ xh,
                                               const f16* __restrict__ Wt,
                                               const float* __restrict__ a,
                                               f16* __restrict__ h,
                                               float* __restrict__ f,
                                               float* __restrict__ g) {
    __shared__ __align__(16) f16 As[64][136];
    __shared__ __align__(16) f16 Bs[64][136];
    __shared__ float sf[2][64], sg[2][64];
    const int tid = threadIdx.x;
    const int n0 = blockIdx.x * 64;
    const int m0 = blockIdx.y * 64;
    const int srow = tid >> 2, sseg = (tid & 3) * 8;
    const int w = tid >> 6, lane = tid & 63;
    const int wm = (w & 1) * 32, wn = (w >> 1) * 32;
    const int l15 = lane & 15, quad = lane >> 4;

    f16x8 pa[4], pb[4];
#pragma unroll
    for (int j = 0; j < 4; ++j) {
        pa[j] = *(const f16x8*)&xh[(size_t)(m0 + srow) * FIN + j * 32 + sseg];
        pb[j] = *(const f16x8*)&Wt[(size_t)(n0 + srow) * FIN + j * 32 + sseg];
    }

    f32x4 acc[2][2] = {};
    for (int k0 = 0; k0 < FIN; k0 += 128) {
        __syncthreads();
#pragma unroll
        for (int j = 0; j < 4; ++j) {
            *(f16x8*)&As[srow][j * 32 + sseg] = pa[j];
            *(f16x8*)&Bs[srow][j * 32 + sseg] = pb[j];
        }
        __syncthreads();
        if (k0 + 128 < FIN) {
#pragma unroll
            for (int j = 0; j < 4; ++j) {
                pa[j] = *(const f16x8*)&xh[(size_t)(m0 + srow) * FIN + k0 + 128 + j * 32 + sseg];
                pb[j] = *(const f16x8*)&Wt[(size_t)(n0 + srow) * FIN + k0 + 128 + j * 32 + sseg];
            }
        }
#pragma unroll
        for (int kk = 0; kk < 4; ++kk) {
            f16x8 af[2], bf[2];
#pragma unroll
            for (int ti = 0; ti < 2; ++ti)
                af[ti] = *(const f16x8*)&As[wm + ti * 16 + l15][kk * 32 + quad * 8];
#pragma unroll
            for (int tj = 0; tj < 2; ++tj)
                bf[tj] = *(const f16x8*)&Bs[wn + tj * 16 + l15][kk * 32 + quad * 8];
#pragma unroll
            for (int ti = 0; ti < 2; ++ti)
#pragma unroll
                for (int tj = 0; tj < 2; ++tj)
                    acc[ti][tj] = __builtin_amdgcn_mfma_f32_16x16x32_f16(af[ti], bf[tj], acc[ti][tj], 0, 0, 0);
        }
    }
#pragma unroll
    for (int ti = 0; ti < 2; ++ti)
#pragma unroll
        for (int tj = 0; tj < 2; ++tj) {
            const int col = n0 + wn + tj * 16 + l15;
#pragma unroll
            for (int r = 0; r < 4; ++r) {
                const int row = m0 + wm + ti * 16 + quad * 4 + r;
                h[(size_t)row * FOUT + col] = (f16)acc[ti][tj][r];
            }
        }
    const float a1c0 = a[n0 + wn + l15];
    const float a1c1 = a[n0 + wn + 16 + l15];
    const float a2c0 = a[FOUT + n0 + wn + l15];
    const float a2c1 = a[FOUT + n0 + wn + 16 + l15];
    const int wnIdx = w >> 1;
#pragma unroll
    for (int ti = 0; ti < 2; ++ti) {
        float pf[4], pg[4];
#pragma unroll
        for (int r = 0; r < 4; ++r) {
            pf[r] = acc[ti][0][r] * a1c0 + acc[ti][1][r] * a1c1;
            pg[r] = acc[ti][0][r] * a2c0 + acc[ti][1][r] * a2c1;
        }
#pragma unroll
        for (int off = 8; off >= 1; off >>= 1)
#pragma unroll
            for (int r = 0; r < 4; ++r) {
                pf[r] += __shfl_xor(pf[r], off, 16);
                pg[r] += __shfl_xor(pg[r], off, 16);
            }
        if (l15 == 0)
#pragma unroll
            for (int r = 0; r < 4; ++r) {
                sf[wnIdx][wm + ti * 16 + quad * 4 + r] = pf[r];
                sg[wnIdx][wm + ti * 16 + quad * 4 + r] = pg[r];
            }
    }
    __syncthreads();
    if (tid < 64) {
        atomicAdd(&f[m0 + tid], sf[0][tid] + sf[1][tid]);
        atomicAdd(&g[m0 + tid], sg[0][tid] + sg[1][tid]);
    }
}

// ---- rank + scatter: rank_j = #{i: g_i<g_j || (==, i<j)} ----
__global__ __launch_bounds__(256) void rank_scatter(const float* __restrict__ g,
                                                    float* __restrict__ gs,
                                                    int* __restrict__ perm) {
    const int t = threadIdx.x;
    const int jl = t & 31;
    const int seg = t >> 5;
    const int j = blockIdx.x * 32 + jl;
    const float gj = g[j];
    const int base = seg * (NROWS / 8);
    int cnt = 0;
    for (int r = 0; r < NROWS / 8; r += 4) {
        const float4 v = *(const float4*)&g[base + r];
        const int i0 = base + r;
        cnt += (v.x < gj) || (v.x == gj && (i0 + 0) < j);
        cnt += (v.y < gj) || (v.y == gj && (i0 + 1) < j);
        cnt += (v.z < gj) || (v.z == gj && (i0 + 2) < j);
        cnt += (v.w < gj) || (v.w == gj && (i0 + 3) < j);
    }
    __shared__ int part[8][32];
    part[seg][jl] = cnt;
    __syncthreads();
    if (seg == 0) {
        int rank = 0;
#pragma unroll
        for (int s = 0; s < 8; ++s) rank += part[s][jl];
        gs[rank] = gj;
        perm[rank] = j;
    }
}

// ---- scan pass 1 (blocks 0-511): per-chunk sums; blocks 512-543: n0 searches ----
__global__ __launch_bounds__(256) void scan_pass1(const f16* __restrict__ h,
                                                  const int* __restrict__ perm,
                                                  const float* __restrict__ gs,
                                                  const float* __restrict__ f,
                                                  float* __restrict__ c0,
                                                  float* __restrict__ c1,
                                                  float* __restrict__ c1s,
                                                  int* __restrict__ n0arr) {
    const int b = blockIdx.x, c = threadIdx.x;
    if (b < NCHUNK) {
        const int base = b * CHROWS;
        __shared__ int p[CHROWS];
        __shared__ float wl[CHROWS];
        if (c < CHROWS) {
            p[c] = perm[base + c];
            wl[c] = expf(gs[base + c] - gs[NROWS - 1]);
        }
        __syncthreads();
        float s0 = 0.f, s1 = 0.f;
        for (int r = 0; r < CHROWS; ++r) {
            float v = (float)h[(size_t)p[r] * FOUT + c];
            s0 += v;
            s1 += wl[r] * v;
        }
        c0[b * FOUT + c] = s0;
        c1[b * FOUT + c] = s1;
        if (c == 0) {
            float t = 0.f;
            for (int r = 0; r < CHROWS; ++r) t += wl[r];
            c1s[b] = t;
        }
    } else {
        const int i = (b - NCHUNK) * 256 + c;   // 0..8191
        const float tt = -f[i];
        int lo = 0, hi = NROWS;
        while (lo < hi) {
            int mid = (lo + hi) >> 1;
            if (gs[mid] <= tt) lo = mid + 1; else hi = mid;
        }
        n0arr[i] = lo;
    }
}

// ---- scan pass 2: 512-length chunk scans, 2 elems/thread blocked ----
__global__ __launch_bounds__(256) void scan_pass2(const float* __restrict__ c0,
                                                  const float* __restrict__ c1,
                                                  const float* __restrict__ c1s,
                                                  float* __restrict__ o0,
                                                  float* __restrict__ o1,
                                                  float* __restrict__ o1s) {
    const int b = blockIdx.x, t = threadIdx.x;
    __shared__ float sb[256];
    if (b < 256) {
        // exclusive PREFIX over 512 chunks of column b of c0
        const float e0 = c0[(2 * t) * FOUT + b];
        const float e1 = c0[(2 * t + 1) * FOUT + b];
        const float local = e0 + e1;
        sb[t] = local;
        __syncthreads();
        for (int off = 1; off < 256; off <<= 1) {
            float add = (t >= off) ? sb[t - off] : 0.f;
            __syncthreads();
            sb[t] += add;
            __syncthreads();
        }
        const float ex = sb[t] - local;   // sum of chunks < 2t
        o0[(2 * t) * FOUT + b] = ex;
        o0[(2 * t + 1) * FOUT + b] = ex + e0;
    } else if (b < 512) {
        const int col = b - 256;
        // exclusive SUFFIX over 512 chunks of column col of c1
        const float e0 = c1[(2 * t) * FOUT + col];
        const float e1 = c1[(2 * t + 1) * FOUT + col];
        const float local = e0 + e1;
        sb[t] = local;
        __syncthreads();
        for (int off = 1; off < 256; off <<= 1) {
            float add = (t + off < 256) ? sb[t + off] : 0.f;
            __syncthreads();
            sb[t] += add;
            __syncthreads();
        }
        const float exs = sb[t] - local;  // sum of chunks > 2t+1
        o1[(2 * t) * FOUT + col] = exs + e1;
        o1[(2 * t + 1) * FOUT + col] = exs;
    } else {
        // exclusive SUFFIX over c1s (scalar)
        const float e0 = c1s[2 * t];
        const float e1 = c1s[2 * t + 1];
        const float local = e0 + e1;
        sb[t] = local;
        __syncthreads();
        for (int off = 1; off < 256; off <<= 1) {
            float add = (t + off < 256) ? sb[t + off] : 0.f;
            __syncthreads();
            sb[t] += add;
            __syncthreads();
        }
        const float exs = sb[t] - local;
        o1s[2 * t] = exs + e1;
        o1s[2 * t + 1] = exs;
    }
}

// ---- scan pass 3: element-granular P0 / S1 (stored f16) / S1s ----
__global__ __launch_bounds__(256) void scan_pass3(const f16* __restrict__ h,
                                                  const int* __restrict__ perm,
                                                  const float* __restrict__ gs,
                                                  const float* __restrict__ o0,
                                                  const float* __restrict__ o1,
                                                  const float* __restrict__ o1s,
                                                  f16* __restrict__ P0,
                                                  f16* __restrict__ S1,
                                                  float* __restrict__ S1s) {
    const int k = blockIdx.x, c = threadIdx.x;
    const int base = k * CHROWS;
    __shared__ int p[CHROWS];
    __shared__ float wl[CHROWS];
    if (c < CHROWS) {
        p[c] = perm[base + c];
        wl[c] = expf(gs[base + c] - gs[NROWS - 1]);
    }
    __syncthreads();
    float run0 = o0[k * FOUT + c];
    for (int r = 0; r < CHROWS; ++r) {
        P0[(size_t)(base + r) * FOUT + c] = (f16)run0;
        run0 += (float)h[(size_t)p[r] * FOUT + c];
    }
    float run1 = o1[k * FOUT + c];
    for (int r = CHROWS - 1; r >= 0; --r) {
        run1 += wl[r] * (float)h[(size_t)p[r] * FOUT + c];
        S1[(size_t)(base + r) * FOUT + c] = (f16)run1;
    }
    if (c == 0) {
        float rs = o1s[k];
        for (int r = CHROWS - 1; r >= 0; --r) { rs += wl[r]; S1s[base + r] = rs; }
    }
    if (k == NCHUNK - 1) {
        P0[(size_t)NROWS * FOUT + c] = (f16)run0;   // total column sum
        S1[(size_t)NROWS * FOUT + c] = (f16)0.f;
        if (c == 0) S1s[NROWS] = 0.f;
    }
}

// ---- final: streaming combine + ELU, 4 rows/block ----
__global__ __launch_bounds__(256) void final_kernel(const float* __restrict__ f,
                                                    const float* __restrict__ gs,
                                                    const int* __restrict__ n0arr,
                                                    const f16* __restrict__ P0,
                                                    const f16* __restrict__ S1,
                                                    const float* __restrict__ S1s,
                                                    float* __restrict__ out) {
    const int b = blockIdx.x, c = threadIdx.x;
    const float gm = gs[NROWS - 1];
#pragma unroll
    for (int rr = 0; rr < 4; ++rr) {
        const int i = b * 4 + rr;
        const float fi = f[i];
        const int n0 = n0arr[i];
        const float m = fmaxf(0.f, fi + gm);
        const float A = expf(-m);
        const float B = expf(fi + gm - m);
        const float denom = A * (float)n0 + B * S1s[n0];
        const float numer = A * (float)P0[(size_t)n0 * FOUT + c]
                          + B * (float)S1[(size_t)n0 * FOUT + c];
        const float v = numer / denom;
        out[(size_t)i * FOUT + c] = v > 0.f ? v : expm1f(v);
    }
}

extern "C" void kernel_launch(void* const* d_in, const int* in_sizes, int n_in,
                              void* d_out, int out_size, void* d_ws, size_t ws_size,
                              hipStream_t stream) {
    (void)in_sizes; (void)n_in; (void)out_size; (void)ws_size;
    const float* x = (const float*)d_in[0];
    const float* W = (const float*)d_in[1];
    const float* a = (const float*)d_in[2];
    float* out = (float*)d_out;

    char* ws = (char*)d_ws;
    size_t off = 0;
    auto alloc = [&](size_t bytes) -> void* {
        void* p = ws + off;
        off += (bytes + 255) & ~(size_t)255;
        return p;
    };
    f16*   xh   = (f16*)alloc((size_t)NROWS * FIN * 2);
    f16*   Wt   = (f16*)alloc((size_t)FOUT * FIN * 2);
    f16*   h    = (f16*)alloc((size_t)NROWS * FOUT * 2);
    f16*   P0   = (f16*)alloc((size_t)(NROWS + 1) * FOUT * 2);
    f16*   S1   = (f16*)alloc((size_t)(NROWS + 1) * FOUT * 2);
    float* fg   = (float*)alloc(2 * NROWS * 4);
    float* f    = fg;
    float* g    = fg + NROWS;
    float* gs   = (float*)alloc(NROWS * 4);
    int*   perm = (int*)alloc(NROWS * 4);
    int*   n0arr= (int*)alloc(NROWS * 4);
    float* c0   = (float*)alloc(NCHUNK * FOUT * 4);
    float* c1   = (float*)alloc(NCHUNK * FOUT * 4);
    float* o0   = (float*)alloc(NCHUNK * FOUT * 4);
    float* o1   = (float*)alloc(NCHUNK * FOUT * 4);
    float* c1s  = (float*)alloc(NCHUNK * 4);
    float* o1s  = (float*)alloc(NCHUNK * 4);
    float* S1s  = (float*)alloc((NROWS + 1) * 4);

    prep<<<512, 256, 0, stream>>>(x, W, xh, Wt, fg);
    gemm_fg<<<dim3(FOUT / 64, NROWS / 64), 256, 0, stream>>>(xh, Wt, a, h, f, g);
    rank_scatter<<<NROWS / 32, 256, 0, stream>>>(g, gs, perm);
    scan_pass1<<<NCHUNK + 32, 256, 0, stream>>>(h, perm, gs, f, c0, c1, c1s, n0arr);
    scan_pass2<<<513, 256, 0, stream>>>(c0, c1, c1s, o0, o1, o1s);
    scan_pass3<<<NCHUNK, 256, 0, stream>>>(h, perm, gs, o0, o1, o1s, P0, S1, S1s);
    final_kernel<<<NROWS / 4, 256, 0, stream>>>(f, gs, n0arr, P0, S1, S1s, out);
}